// Round 1
// baseline (4173.603 us; speedup 1.0000x reference)
//
#include <hip/hip_runtime.h>
#include <hip/hip_bf16.h>

// TreeLSTM (child-sum, complete binary tree, DEPTH=8) on MI355X.
// Round 1: correct fp32 tiled-GEMM baseline. h activations stored bf16.
// Structure per level: [hsum] -> iou GEMM -> iou+=h GEMM -> fxo GEMM -> fh GEMM -> pointwise(LN).

#define Hdim 768
#define Bsz  128
#define DEPTH 8

typedef __hip_bfloat16 bf16;

__device__ inline float b2f(unsigned short u) {
    union { unsigned int i; float f; } v; v.i = ((unsigned int)u) << 16; return v.f;
}

__device__ inline float4 loadA4(const float* p) { return *(const float4*)p; }
__device__ inline float4 loadA4(const bf16* p) {
    const ushort4 u = *(const ushort4*)p;
    float4 r; r.x = b2f(u.x); r.y = b2f(u.y); r.z = b2f(u.z); r.w = b2f(u.w); return r;
}

// C[M,N] = A[M,K] * W[N,K]^T (+bias) (+C if accum) (+addv rows)
// A rows mapped: row r -> A + (r>>ashift)*astride_b + (r&((1<<ashift)-1))*astride_r
// M, N multiples of 64; K multiple of 16. No bounds checks needed.
template <typename AT>
__global__ __launch_bounds__(256) void gemm_nt(
    const AT* __restrict__ A, int ashift, long astride_b, long astride_r,
    const float* __restrict__ W,          // [N,K] row-major
    const float* __restrict__ bias,       // [N] or null
    float* __restrict__ C, int ldc,
    int K, int accum,
    const float* __restrict__ addv, long add_stride)
{
    __shared__ float As[16][68];
    __shared__ float Ws[16][68];
    const int t  = threadIdx.x;
    const int bm = blockIdx.y, bn = blockIdx.x;
    const int lr = t >> 2;          // 0..63: row within tile for loading
    const int lk = (t & 3) << 2;    // 0,4,8,12: k offset for loading
    const int arow = (bm << 6) + lr;
    const AT* Ap = A + (long)(arow >> ashift) * astride_b
                     + (long)(arow & ((1 << ashift) - 1)) * astride_r;
    const float* Wp = W + (long)((bn << 6) + lr) * K;
    const int ty = (t >> 4) << 2;   // 0..60 step 4
    const int tx = (t & 15) << 2;

    float acc[4][4];
#pragma unroll
    for (int i = 0; i < 4; i++)
#pragma unroll
        for (int j = 0; j < 4; j++) acc[i][j] = 0.f;

    for (int k0 = 0; k0 < K; k0 += 16) {
        float4 av = loadA4(Ap + k0 + lk);
        float4 wv = *(const float4*)(Wp + k0 + lk);
        As[lk + 0][lr] = av.x; As[lk + 1][lr] = av.y;
        As[lk + 2][lr] = av.z; As[lk + 3][lr] = av.w;
        Ws[lk + 0][lr] = wv.x; Ws[lk + 1][lr] = wv.y;
        Ws[lk + 2][lr] = wv.z; Ws[lk + 3][lr] = wv.w;
        __syncthreads();
#pragma unroll
        for (int k = 0; k < 16; k++) {
            float4 a = *(const float4*)&As[k][ty];
            float4 w = *(const float4*)&Ws[k][tx];
            acc[0][0] += a.x * w.x; acc[0][1] += a.x * w.y; acc[0][2] += a.x * w.z; acc[0][3] += a.x * w.w;
            acc[1][0] += a.y * w.x; acc[1][1] += a.y * w.y; acc[1][2] += a.y * w.z; acc[1][3] += a.y * w.w;
            acc[2][0] += a.z * w.x; acc[2][1] += a.z * w.y; acc[2][2] += a.z * w.z; acc[2][3] += a.z * w.w;
            acc[3][0] += a.w * w.x; acc[3][1] += a.w * w.y; acc[3][2] += a.w * w.z; acc[3][3] += a.w * w.w;
        }
        __syncthreads();
    }

#pragma unroll
    for (int i = 0; i < 4; i++) {
        const int row = (bm << 6) + ty + i;
#pragma unroll
        for (int j = 0; j < 4; j++) {
            const int col = (bn << 6) + tx + j;
            float v = acc[i][j];
            if (bias) v += bias[col];
            if (accum) v += C[(long)row * ldc + col];
            if (addv)  v += addv[(long)row * add_stride + col];
            C[(long)row * ldc + col] = v;
        }
    }
}

// hsum[m][j] = h[2m][j] + h[2m+1][j]   grid (3, M), block 256
__global__ __launch_bounds__(256) void hsum_kernel(const bf16* __restrict__ hp,
                                                   float* __restrict__ out) {
    const int m = blockIdx.y;
    const int j = blockIdx.x * 256 + threadIdx.x;
    out[(long)m * Hdim + j] = __bfloat162float(hp[(long)(2 * m) * Hdim + j]) +
                              __bfloat162float(hp[(long)(2 * m + 1) * Hdim + j]);
}

__device__ inline float sigf(float x) { return 1.f / (1.f + __expf(-x)); }
__device__ inline float tanh_fast(float x) { return 2.f / (1.f + __expf(-2.f * x)) - 1.f; }

__device__ inline void block_reduce2(float& a, float& b, float* s) {
#pragma unroll
    for (int off = 32; off > 0; off >>= 1) {
        a += __shfl_down(a, off, 64);
        b += __shfl_down(b, off, 64);
    }
    const int lane = threadIdx.x & 63, w = threadIdx.x >> 6;
    __syncthreads();
    if (lane == 0) { s[w] = a; s[w + 4] = b; }
    __syncthreads();
    a = s[0] + s[1] + s[2] + s[3];
    b = s[4] + s[5] + s[6] + s[7];
}

// One block (256 thr) per row m. 768 = 3*256 elements/thread-strided.
__global__ __launch_bounds__(256) void pointwise_kernel(
    const float* __restrict__ iou,   // [M,3H]
    const float* __restrict__ fxo,   // [M,H]   (internal only)
    const float* __restrict__ fh,    // [M,2,H] (internal only)
    const bf16*  __restrict__ hprev, // child rows 2m,2m+1 (internal only)
    const float* __restrict__ bfh,   // [H]
    const float* __restrict__ gc, const float* __restrict__ bc,
    const float* __restrict__ gh, const float* __restrict__ bh,
    bf16* __restrict__ hout, int internal)
{
    __shared__ float sred[8];
    const int m = blockIdx.x;
    const float* iour = iou + (long)m * 3 * Hdim;
    float cv[3], ov[3], hv[3];
    float ssum = 0.f, ssq = 0.f;
#pragma unroll
    for (int tI = 0; tI < 3; tI++) {
        const int j = threadIdx.x + tI * 256;
        const float i_ = sigf(iour[j]);
        ov[tI] = iour[Hdim + j];
        const float u_ = tanh_fast(iour[2 * Hdim + j]);
        float c = i_ * u_;
        if (internal) {
            const float fx = fxo[(long)m * Hdim + j];
            const float bfhj = bfh[j];
            const float f0 = sigf(fx + fh[(long)m * 2 * Hdim + j] + bfhj);
            const float f1 = sigf(fx + fh[(long)m * 2 * Hdim + Hdim + j] + bfhj);
            const float c0 = __bfloat162float(hprev[(long)(2 * m) * Hdim + j]);
            const float c1 = __bfloat162float(hprev[(long)(2 * m + 1) * Hdim + j]);
            c += f0 * c0 + f1 * c1;
        }
        cv[tI] = c; ssum += c; ssq += c * c;
    }
    block_reduce2(ssum, ssq, sred);
    const float mean = ssum / Hdim;
    const float rstd = rsqrtf(ssq / Hdim - mean * mean + 1e-5f);
    float hs = 0.f, hq = 0.f;
#pragma unroll
    for (int tI = 0; tI < 3; tI++) {
        const int j = threadIdx.x + tI * 256;
        const float cn = (cv[tI] - mean) * rstd * gc[j] + bc[j];
        const float h = sigf(ov[tI]) * tanh_fast(cn);
        hv[tI] = h; hs += h; hq += h * h;
    }
    block_reduce2(hs, hq, sred);
    const float mh = hs / Hdim;
    const float rh = rsqrtf(hq / Hdim - mh * mh + 1e-5f);
#pragma unroll
    for (int tI = 0; tI < 3; tI++) {
        const int j = threadIdx.x + tI * 256;
        hout[(long)m * Hdim + j] = __float2bfloat16((hv[tI] - mh) * rh * gh[j] + bh[j]);
    }
}

extern "C" void kernel_launch(void* const* d_in, const int* in_sizes, int n_in,
                              void* d_out, int out_size, void* d_ws, size_t ws_size,
                              hipStream_t stream) {
    (void)in_sizes; (void)n_in; (void)out_size; (void)ws_size;
    const float* x      = (const float*)d_in[0];   // [128,255,768]
    const float* Wioux  = (const float*)d_in[1];   // [8,2304,768]
    const float* b_ioux = (const float*)d_in[2];   // [8,2304]
    const float* Wiouh  = (const float*)d_in[3];   // [8,2304,768]
    const float* Wfx    = (const float*)d_in[4];   // [8,768,768]
    const float* b_fx   = (const float*)d_in[5];   // [8,768]
    const float* Wfh    = (const float*)d_in[6];   // [8,768,768]
    const float* b_fh   = (const float*)d_in[7];   // [8,768]
    const float* ln_c_g = (const float*)d_in[8];
    const float* ln_c_b = (const float*)d_in[9];
    const float* ln_h_g = (const float*)d_in[10];
    const float* ln_h_b = (const float*)d_in[11];
    const float* Wout   = (const float*)d_in[12];  // [768,768]
    const float* b_out  = (const float*)d_in[13];  // [768]
    float* out = (float*)d_out;                    // [128,768]

    // Workspace layout (total ~216 MB)
    char* p = (char*)d_ws;
    bf16* hA = (bf16*)p;                 p += (size_t)16384 * Hdim * 2;  // 25.2 MB
    bf16* hB = (bf16*)p;                 p += (size_t)16384 * Hdim * 2;  // 25.2 MB
    float* hsum = (float*)p;             p += (size_t)8192 * Hdim * 4;   // 25.2 MB
    float* iou  = (float*)p;             p += (size_t)8192 * 3 * Hdim * 4; // 75.5 MB
    float* fxo  = (float*)p;             p += (size_t)8192 * Hdim * 4;   // 25.2 MB
    float* fh   = (float*)p;             p += (size_t)8192 * 2 * Hdim * 4; // 50.3 MB

    const long xrow_b = 255L * Hdim;  // per-batch row stride in x

    // ---- Level 7 (leaves), 2 chunks of 64 batches to bound iou buffer ----
    for (int c = 0; c < 2; c++) {
        const int M = 8192;
        const float* Ax = x + 127L * Hdim + (long)c * 64 * xrow_b;
        gemm_nt<float><<<dim3(36, M / 64), 256, 0, stream>>>(
            Ax, 7, xrow_b, (long)Hdim,
            Wioux + 7L * 3 * Hdim * Hdim, b_ioux + 7L * 3 * Hdim,
            iou, 3 * Hdim, Hdim, 0, nullptr, 0);
        pointwise_kernel<<<M, 256, 0, stream>>>(
            iou, nullptr, nullptr, nullptr, b_fh + 7 * Hdim,
            ln_c_g + 7 * Hdim, ln_c_b + 7 * Hdim, ln_h_g + 7 * Hdim, ln_h_b + 7 * Hdim,
            hA + (long)c * 8192 * Hdim, 0);
    }

    bf16* hp = hA;
    bf16* hc = hB;
    for (int l = 6; l >= 0; l--) {
        const int n = 1 << l;
        const int M = Bsz * n;
        const float* Ax = x + (long)(n - 1) * Hdim;
        const float* Wioux_l = Wioux + (long)l * 3 * Hdim * Hdim;
        const float* Wiouh_l = Wiouh + (long)l * 3 * Hdim * Hdim;
        const float* Wfx_l   = Wfx + (long)l * Hdim * Hdim;
        const float* Wfh_l   = Wfh + (long)l * Hdim * Hdim;

        hsum_kernel<<<dim3(3, M), 256, 0, stream>>>(hp, hsum);
        // iou = xs @ Wioux^T + b_ioux
        gemm_nt<float><<<dim3(36, M / 64), 256, 0, stream>>>(
            Ax, l, xrow_b, (long)Hdim, Wioux_l, b_ioux + (long)l * 3 * Hdim,
            iou, 3 * Hdim, Hdim, 0, nullptr, 0);
        // iou += hsum @ Wiouh^T
        gemm_nt<float><<<dim3(36, M / 64), 256, 0, stream>>>(
            hsum, 0, (long)Hdim, 0, Wiouh_l, nullptr,
            iou, 3 * Hdim, Hdim, 1, nullptr, 0);
        // fxo = xs @ Wfx^T + b_fx
        gemm_nt<float><<<dim3(12, M / 64), 256, 0, stream>>>(
            Ax, l, xrow_b, (long)Hdim, Wfx_l, b_fx + (long)l * Hdim,
            fxo, Hdim, Hdim, 0, nullptr, 0);
        // fh[2M,H] = hprev @ Wfh^T   (child rows are exactly rows 2m,2m+1)
        gemm_nt<bf16><<<dim3(12, 2 * M / 64), 256, 0, stream>>>(
            hp, 0, (long)Hdim, 0, Wfh_l, nullptr,
            fh, Hdim, Hdim, 0, nullptr, 0);
        pointwise_kernel<<<M, 256, 0, stream>>>(
            iou, fxo, fh, hp, b_fh + (long)l * Hdim,
            ln_c_g + (long)l * Hdim, ln_c_b + (long)l * Hdim,
            ln_h_g + (long)l * Hdim, ln_h_b + (long)l * Hdim, hc, 1);
        bf16* tmp = hp; hp = hc; hc = tmp;
    }

    // out = h_root @ Wout^T + b_out + x[:,0]
    gemm_nt<bf16><<<dim3(12, 2), 256, 0, stream>>>(
        hp, 0, (long)Hdim, 0, Wout, b_out,
        out, Hdim, Hdim, 0, x, xrow_b);
}

// Round 2
// 1244.799 us; speedup vs baseline: 3.3528x; 3.3528x over previous
//
#include <hip/hip_runtime.h>
#include <hip/hip_bf16.h>

// TreeLSTM (child-sum, complete binary tree, DEPTH=8) on MI355X.
// Round 2: bf16 MFMA GEMM core (m97 structure: 128x128x32 tile,
// global_load_lds width-16 staging, 16x16x32 bf16 MFMA, 4x4 acc/wave).
// Per level: build A_cat=[xs|hsum] -> fused iou+fxo GEMM (N=3072) ->
// fh GEMM -> pointwise(LN). Weights converted to bf16 once per launch.

#define Hdim 768
#define DEPTH 8

typedef __hip_bfloat16 bf16;
typedef __attribute__((ext_vector_type(8))) short short8;
typedef __attribute__((ext_vector_type(4))) float floatx4;

__device__ inline float b2f(unsigned short u) {
    union { unsigned int i; float f; } v; v.i = ((unsigned int)u) << 16; return v.f;
}
__device__ inline unsigned short f2bu(float f) {
    __hip_bfloat16 h = __float2bfloat16(f);
    return *(unsigned short*)&h;
}
__device__ inline ushort4 cvt4(float4 v) {
    ushort4 o; o.x = f2bu(v.x); o.y = f2bu(v.y); o.z = f2bu(v.z); o.w = f2bu(v.w);
    return o;
}

// ---------------- weight conversion ----------------
// W_cat[l] : [3072][1536] = [[Wioux[l] | Wiouh[l]]; [Wfx[l] | 0]]
__global__ __launch_bounds__(384) void conv_wcat(
    const float* __restrict__ Wioux, const float* __restrict__ Wiouh,
    const float* __restrict__ Wfx, bf16* __restrict__ W_cat)
{
    const int row = blockIdx.x;          // 0 .. 8*3072-1
    const int l = row / 3072;
    const int g = row % 3072;
    const int t = threadIdx.x;           // 0..383, 4 cols each
    const int k2 = t << 2;
    float4 v;
    if (g < 2304) {
        const float* src = (k2 < 768)
            ? Wioux + ((long)l * 2304 + g) * 768 + k2
            : Wiouh + ((long)l * 2304 + g) * 768 + (k2 - 768);
        v = *(const float4*)src;
    } else if (k2 < 768) {
        v = *(const float4*)(Wfx + ((long)l * 768 + (g - 2304)) * 768 + k2);
    } else {
        v = make_float4(0.f, 0.f, 0.f, 0.f);
    }
    ((ushort4*)(W_cat + (long)row * 1536))[t] = cvt4(v);
}

__global__ __launch_bounds__(256) void conv_f2b(
    const float* __restrict__ src, bf16* __restrict__ dst, long n4)
{
    long i = (long)blockIdx.x * 256 + threadIdx.x;
    const long stride = (long)gridDim.x * 256;
    for (; i < n4; i += stride)
        ((ushort4*)dst)[i] = cvt4(((const float4*)src)[i]);
}

__global__ __launch_bounds__(256) void build_bcat(
    const float* __restrict__ b_ioux, const float* __restrict__ b_fx,
    float* __restrict__ b_cat)
{
    const int i = blockIdx.x * 256 + threadIdx.x;   // 8*3072
    const int l = i / 3072, g = i % 3072;
    b_cat[i] = (g < 2304) ? b_ioux[l * 2304 + g] : b_fx[l * 768 + (g - 2304)];
}

// ---------------- A_cat build: [xs | h0+h1] ----------------
__global__ __launch_bounds__(192) void build_a(
    const float* __restrict__ x, const bf16* __restrict__ hprev,
    bf16* __restrict__ A_cat, int l, int m0, int internal)
{
    const int m = blockIdx.x;
    const int idx = m0 + m;
    const int nm1 = (1 << l) - 1;
    const int b = idx >> l;
    const int j = idx & nm1;
    const float* xr = x + ((long)b * 255 + nm1 + j) * Hdim;
    const int lda = internal ? 1536 : 768;
    bf16* ar = A_cat + (long)m * lda;
    const int t = threadIdx.x;  // 0..191, 4 elems each
    ((ushort4*)ar)[t] = cvt4(((const float4*)xr)[t]);
    if (internal) {
        const ushort4 a4 = ((const ushort4*)(hprev + (long)(2 * idx) * Hdim))[t];
        const ushort4 c4 = ((const ushort4*)(hprev + (long)(2 * idx + 1) * Hdim))[t];
        ushort4 s;
        s.x = f2bu(b2f(a4.x) + b2f(c4.x));
        s.y = f2bu(b2f(a4.y) + b2f(c4.y));
        s.z = f2bu(b2f(a4.z) + b2f(c4.z));
        s.w = f2bu(b2f(a4.w) + b2f(c4.w));
        ((ushort4*)(ar + 768))[t] = s;
    }
}

// ---------------- MFMA GEMM: C[M,N] = A[M,K] @ W[N,K]^T (+bias) (+addv) ----------------
// 128x128 tile, BK=32, 256 threads = 4 waves, each wave 64x64 as 4x4 16x16x32 MFMA.
// M,N multiples of 128; K multiple of 32.
__global__ __launch_bounds__(256) void gemm_mfma(
    const bf16* __restrict__ A, int lda,
    const bf16* __restrict__ W, int ldw,
    const float* __restrict__ bias,
    void* __restrict__ Cout, int ldc, int c_fp32,
    int K,
    const float* __restrict__ addv, long add_stride)
{
    __shared__ __align__(16) bf16 As[128 * 32];
    __shared__ __align__(16) bf16 Ws[128 * 32];
    const int t = threadIdx.x;
    const int wave = t >> 6, lane = t & 63;
    const long m_blk = (long)blockIdx.y << 7;
    const long n_blk = (long)blockIdx.x << 7;

    // staging: wave w covers tile rows [32w, 32w+32), two 16-row instrs
    const int srow = (wave << 5) + (lane >> 2);
    const int sbyte = (lane & 3) << 4;
    const char* gA = (const char*)(A + (m_blk + srow) * (long)lda) + sbyte;
    const char* gW = (const char*)(W + (n_blk + srow) * (long)ldw) + sbyte;
    const long aRow16 = (long)lda * 32;   // 16 rows * 2 bytes
    const long wRow16 = (long)ldw * 32;
    bf16* lA = As + (wave << 10);         // wave * 2048 B
    bf16* lW = Ws + (wave << 10);

    floatx4 zero = {0.f, 0.f, 0.f, 0.f};
    floatx4 acc[4][4];
#pragma unroll
    for (int i = 0; i < 4; i++)
#pragma unroll
        for (int j = 0; j < 4; j++) acc[i][j] = zero;

    const int mrow = (wave & 1) << 6;
    const int ncol = (wave >> 1) << 6;
    const short* AsS = (const short*)As;
    const short* WsS = (const short*)Ws;
    const int fm = lane & 15;
    const int fk = (lane >> 4) << 3;      // element offset in row

    for (int k0 = 0; k0 < K; k0 += 32) {
        __builtin_amdgcn_global_load_lds(
            (const __attribute__((address_space(1))) unsigned int*)gA,
            (__attribute__((address_space(3))) unsigned int*)lA, 16, 0, 0);
        __builtin_amdgcn_global_load_lds(
            (const __attribute__((address_space(1))) unsigned int*)(gA + aRow16),
            (__attribute__((address_space(3))) unsigned int*)(lA + 512), 16, 0, 0);
        __builtin_amdgcn_global_load_lds(
            (const __attribute__((address_space(1))) unsigned int*)gW,
            (__attribute__((address_space(3))) unsigned int*)lW, 16, 0, 0);
        __builtin_amdgcn_global_load_lds(
            (const __attribute__((address_space(1))) unsigned int*)(gW + wRow16),
            (__attribute__((address_space(3))) unsigned int*)(lW + 512), 16, 0, 0);
        gA += 64; gW += 64;
        __syncthreads();

        short8 af[4], bfr[4];
#pragma unroll
        for (int i = 0; i < 4; i++) {
            af[i]  = *(const short8*)(AsS + (mrow + i * 16 + fm) * 32 + fk);
            bfr[i] = *(const short8*)(WsS + (ncol + i * 16 + fm) * 32 + fk);
        }
#pragma unroll
        for (int i = 0; i < 4; i++)
#pragma unroll
            for (int j = 0; j < 4; j++)
                acc[i][j] = __builtin_amdgcn_mfma_f32_16x16x32_bf16(
                    af[i], bfr[j], acc[i][j], 0, 0, 0);
        __syncthreads();
    }

    // epilogue: C/D layout col = lane&15, row = (lane>>4)*4 + reg
    const int crow0 = (lane >> 4) << 2;
    const int ccol = lane & 15;
#pragma unroll
    for (int i = 0; i < 4; i++) {
#pragma unroll
        for (int j = 0; j < 4; j++) {
            const long col = n_blk + ncol + j * 16 + ccol;
            const float bv = bias ? bias[col] : 0.f;
#pragma unroll
            for (int r = 0; r < 4; r++) {
                const long row = m_blk + mrow + i * 16 + crow0 + r;
                float v = acc[i][j][r] + bv;
                if (addv) v += addv[row * add_stride + col];
                if (c_fp32) ((float*)Cout)[row * (long)ldc + col] = v;
                else ((bf16*)Cout)[row * (long)ldc + col] = __float2bfloat16(v);
            }
        }
    }
}

// ---------------- pointwise: gates + forget + 2x LayerNorm ----------------
__device__ inline float sigf(float x) { return 1.f / (1.f + __expf(-x)); }
__device__ inline float tanh_fast(float x) { return 2.f / (1.f + __expf(-2.f * x)) - 1.f; }

__device__ inline void block_reduce2(float& a, float& b, float* s) {
#pragma unroll
    for (int off = 32; off > 0; off >>= 1) {
        a += __shfl_down(a, off, 64);
        b += __shfl_down(b, off, 64);
    }
    const int lane = threadIdx.x & 63, w = threadIdx.x >> 6;
    __syncthreads();
    if (lane == 0) { s[w] = a; s[w + 4] = b; }
    __syncthreads();
    a = s[0] + s[1] + s[2] + s[3];
    b = s[4] + s[5] + s[6] + s[7];
}

__global__ __launch_bounds__(256) void pointwise(
    const float* __restrict__ C, int ldc,     // [Mc,ldc]: i|o|u|(fxo)
    const bf16* __restrict__ fh,              // [2Mc,768] or null
    const bf16* __restrict__ hprev,           // children base (offset 2*m0) or null
    const float* __restrict__ bfh,
    const float* __restrict__ gc, const float* __restrict__ bc,
    const float* __restrict__ gh, const float* __restrict__ bh,
    bf16* __restrict__ hout)                  // already offset by m0
{
    __shared__ float sred[8];
    const int m = blockIdx.x;
    const float* cr = C + (long)m * ldc;
    float cv[3], ov[3], hv[3];
    float ssum = 0.f, ssq = 0.f;
#pragma unroll
    for (int tI = 0; tI < 3; tI++) {
        const int j = threadIdx.x + tI * 256;
        const float i_ = sigf(cr[j]);
        ov[tI] = cr[Hdim + j];
        const float u_ = tanh_fast(cr[2 * Hdim + j]);
        float c = i_ * u_;
        if (fh) {
            const float fx = cr[3 * Hdim + j];
            const float bfhj = bfh[j];
            const float f0 = sigf(fx + b2f(*(const unsigned short*)&fh[(long)(2 * m) * Hdim + j]) + bfhj);
            const float f1 = sigf(fx + b2f(*(const unsigned short*)&fh[(long)(2 * m + 1) * Hdim + j]) + bfhj);
            const float c0 = b2f(*(const unsigned short*)&hprev[(long)(2 * m) * Hdim + j]);
            const float c1 = b2f(*(const unsigned short*)&hprev[(long)(2 * m + 1) * Hdim + j]);
            c += f0 * c0 + f1 * c1;
        }
        cv[tI] = c; ssum += c; ssq += c * c;
    }
    block_reduce2(ssum, ssq, sred);
    const float mean = ssum / Hdim;
    const float rstd = rsqrtf(ssq / Hdim - mean * mean + 1e-5f);
    float hs = 0.f, hq = 0.f;
#pragma unroll
    for (int tI = 0; tI < 3; tI++) {
        const int j = threadIdx.x + tI * 256;
        const float cn = (cv[tI] - mean) * rstd * gc[j] + bc[j];
        const float h = sigf(ov[tI]) * tanh_fast(cn);
        hv[tI] = h; hs += h; hq += h * h;
    }
    block_reduce2(hs, hq, sred);
    const float mh = hs / Hdim;
    const float rh = rsqrtf(hq / Hdim - mh * mh + 1e-5f);
#pragma unroll
    for (int tI = 0; tI < 3; tI++) {
        const int j = threadIdx.x + tI * 256;
        hout[(long)m * Hdim + j] = __float2bfloat16((hv[tI] - mh) * rh * gh[j] + bh[j]);
    }
}

// ---------------- launch ----------------
extern "C" void kernel_launch(void* const* d_in, const int* in_sizes, int n_in,
                              void* d_out, int out_size, void* d_ws, size_t ws_size,
                              hipStream_t stream) {
    (void)in_sizes; (void)n_in; (void)out_size; (void)ws_size;
    const float* x      = (const float*)d_in[0];
    const float* Wioux  = (const float*)d_in[1];
    const float* b_ioux = (const float*)d_in[2];
    const float* Wiouh  = (const float*)d_in[3];
    const float* Wfx    = (const float*)d_in[4];
    const float* b_fx   = (const float*)d_in[5];
    const float* b_fh   = (const float*)d_in[7];
    const float* Wfh    = (const float*)d_in[6];
    const float* ln_c_g = (const float*)d_in[8];
    const float* ln_c_b = (const float*)d_in[9];
    const float* ln_h_g = (const float*)d_in[10];
    const float* ln_h_b = (const float*)d_in[11];
    const float* Wout   = (const float*)d_in[12];
    const float* b_out  = (const float*)d_in[13];
    float* out = (float*)d_out;

    // workspace (~199.5 MB)
    char* p = (char*)d_ws;
    bf16* W_cat   = (bf16*)p; p += 8L * 3072 * 1536 * 2;   // 75.5 MB
    bf16* Wfh_bf  = (bf16*)p; p += 8L * 768 * 768 * 2;     //  9.4 MB
    bf16* Wout_bf = (bf16*)p; p += 768L * 768 * 2;         //  1.2 MB
    float* b_cat  = (float*)p; p += 8L * 3072 * 4;         //  0.1 MB
    bf16* hA      = (bf16*)p; p += 16384L * 768 * 2;       // 25.2 MB
    bf16* hB      = (bf16*)p; p += 8192L * 768 * 2;        // 12.6 MB
    bf16* A_cat   = (bf16*)p; p += 4096L * 1536 * 2;       // 12.6 MB
    float* Cbuf   = (float*)p; p += 4096L * 3072 * 4;      // 50.3 MB
    bf16* fhb     = (bf16*)p; p += 8192L * 768 * 2;        // 12.6 MB

    // --- weight conversions (every launch; ws is re-poisoned) ---
    conv_wcat<<<8 * 3072, 384, 0, stream>>>(Wioux, Wiouh, Wfx, W_cat);
    conv_f2b<<<4608, 256, 0, stream>>>(Wfh, Wfh_bf, 8L * 768 * 768 / 4);
    conv_f2b<<<576, 256, 0, stream>>>(Wout, Wout_bf, 768L * 768 / 4);
    build_bcat<<<96, 256, 0, stream>>>(b_ioux, b_fx, b_cat);

    const int CH = 4096;

    // --- leaf level l=7: M=16384, iou only ---
    for (int c = 0; c < 4; c++) {
        const int m0 = c * CH;
        build_a<<<CH, 192, 0, stream>>>(x, nullptr, A_cat, 7, m0, 0);
        gemm_mfma<<<dim3(18, CH / 128), 256, 0, stream>>>(
            A_cat, 768, W_cat + 7L * 3072 * 1536, 1536, b_cat + 7 * 3072,
            Cbuf, 2304, 1, 768, nullptr, 0);
        pointwise<<<CH, 256, 0, stream>>>(
            Cbuf, 2304, nullptr, nullptr, nullptr,
            ln_c_g + 7 * Hdim, ln_c_b + 7 * Hdim, ln_h_g + 7 * Hdim, ln_h_b + 7 * Hdim,
            hA + (long)m0 * Hdim);
    }

    bf16* hp = hA;
    bf16* hc = hB;
    for (int l = 6; l >= 0; l--) {
        const int M = 128 << l;
        const int nchunk = (M + CH - 1) / CH;
        const int Mc = (M < CH) ? M : CH;
        for (int c = 0; c < nchunk; c++) {
            const int m0 = c * CH;
            build_a<<<Mc, 192, 0, stream>>>(x, hp, A_cat, l, m0, 1);
            gemm_mfma<<<dim3(24, Mc / 128), 256, 0, stream>>>(
                A_cat, 1536, W_cat + (long)l * 3072 * 1536, 1536, b_cat + l * 3072,
                Cbuf, 3072, 1, 1536, nullptr, 0);
            gemm_mfma<<<dim3(6, 2 * Mc / 128), 256, 0, stream>>>(
                hp + (long)2 * m0 * Hdim, 768, Wfh_bf + (long)l * 768 * 768, 768, nullptr,
                fhb, 768, 0, 768, nullptr, 0);
            pointwise<<<Mc, 256, 0, stream>>>(
                Cbuf, 3072, fhb, hp + (long)2 * m0 * Hdim, b_fh + l * Hdim,
                ln_c_g + l * Hdim, ln_c_b + l * Hdim, ln_h_g + l * Hdim, ln_h_b + l * Hdim,
                hc + (long)m0 * Hdim);
        }
        bf16* tmp = hp; hp = hc; hc = tmp;
    }

    // --- output: out = h_root @ Wout^T + b_out + x[:,0] ---
    gemm_mfma<<<dim3(6, 1), 256, 0, stream>>>(
        hp, 768, Wout_bf, 768, b_out,
        out, 768, 1, 768, x, 255L * 768);
}

// Round 3
// 1205.830 us; speedup vs baseline: 3.4612x; 1.0323x over previous
//
#include <hip/hip_runtime.h>
#include <hip/hip_bf16.h>

// TreeLSTM (child-sum, complete binary tree, DEPTH=8) on MI355X.
// Round 3: XOR-swizzled LDS (kills 8-way ds_read bank conflicts), bf16 C
// buffer (halves C round-trip), sibling-pair pointwise fusing hsum + A_cat
// build for the next level. ws ~212 MB (<= 226 MB proven in R1).

#define Hdim 768

typedef __hip_bfloat16 bf16;
typedef __attribute__((ext_vector_type(8))) short short8;
typedef __attribute__((ext_vector_type(4))) float floatx4;

__device__ inline float b2f(unsigned short u) {
    union { unsigned int i; float f; } v; v.i = ((unsigned int)u) << 16; return v.f;
}
__device__ inline float b2f(bf16 h) { return b2f(*(unsigned short*)&h); }
__device__ inline unsigned short f2bu(float f) {
    bf16 h = __float2bfloat16(f);
    return *(unsigned short*)&h;
}
__device__ inline ushort4 cvt4(float4 v) {
    ushort4 o; o.x = f2bu(v.x); o.y = f2bu(v.y); o.z = f2bu(v.z); o.w = f2bu(v.w);
    return o;
}

// ---------------- weight prep ----------------
// W_cat[l] : [3072][1536] = [[Wioux[l] | Wiouh[l]]; [Wfx[l] | 0]]
__global__ __launch_bounds__(384) void conv_wcat(
    const float* __restrict__ Wioux, const float* __restrict__ Wiouh,
    const float* __restrict__ Wfx, bf16* __restrict__ W_cat)
{
    const int row = blockIdx.x;          // 0 .. 8*3072-1
    const int l = row / 3072;
    const int g = row % 3072;
    const int t = threadIdx.x;
    const int k2 = t << 2;
    float4 v;
    if (g < 2304) {
        const float* src = (k2 < 768)
            ? Wioux + ((long)l * 2304 + g) * 768 + k2
            : Wiouh + ((long)l * 2304 + g) * 768 + (k2 - 768);
        v = *(const float4*)src;
    } else if (k2 < 768) {
        v = *(const float4*)(Wfx + ((long)l * 768 + (g - 2304)) * 768 + k2);
    } else {
        v = make_float4(0.f, 0.f, 0.f, 0.f);
    }
    ((ushort4*)(W_cat + (long)row * 1536))[t] = cvt4(v);
}

__global__ __launch_bounds__(256) void conv_f2b(
    const float* __restrict__ src, bf16* __restrict__ dst, long n4)
{
    long i = (long)blockIdx.x * 256 + threadIdx.x;
    const long stride = (long)gridDim.x * 256;
    for (; i < n4; i += stride)
        ((ushort4*)dst)[i] = cvt4(((const float4*)src)[i]);
}

__global__ __launch_bounds__(256) void build_bcat(
    const float* __restrict__ b_ioux, const float* __restrict__ b_fx,
    float* __restrict__ b_cat)
{
    const int i = blockIdx.x * 256 + threadIdx.x;   // 8*3072
    const int l = i / 3072, g = i % 3072;
    b_cat[i] = (g < 2304) ? b_ioux[l * 2304 + g] : b_fx[l * 768 + (g - 2304)];
}

// leaf xs: row m -> x[b, 127+j]  (b=m>>7, j=m&127)
__global__ __launch_bounds__(192) void conv_leaf(const float* __restrict__ x,
                                                 bf16* __restrict__ leafA) {
    const int m = blockIdx.x;
    const int b = m >> 7, j = m & 127;
    const float* xr = x + ((long)b * 255 + 127 + j) * Hdim;
    ((ushort4*)(leafA + (long)m * Hdim))[threadIdx.x] =
        cvt4(((const float4*)xr)[threadIdx.x]);
}

// ---------------- MFMA GEMM ----------------
// C[M,N] = A[M,K] @ W[N,K]^T (+bias) (+addv). 128x128 tile, BK=32,
// 256 thr = 4 waves, 4x4 16x16x32 MFMA per wave. XOR-swizzled LDS chunks.
__global__ __launch_bounds__(256) void gemm_mfma(
    const bf16* __restrict__ A, int lda,
    const bf16* __restrict__ W, int ldw,
    const float* __restrict__ bias,
    void* __restrict__ Cout, int ldc, int c_fp32,
    int K,
    const float* __restrict__ addv, long add_stride)
{
    __shared__ __align__(16) bf16 As[128 * 32];
    __shared__ __align__(16) bf16 Ws[128 * 32];
    const int t = threadIdx.x;
    const int wave = t >> 6, lane = t & 63;
    const long m_blk = (long)blockIdx.y << 7;
    const long n_blk = (long)blockIdx.x << 7;

    // staging: one instr = 64 lanes x 16B = 16 rows of 64B. lane -> (r16,q).
    const int r16 = lane >> 2;
    const int q = lane & 3;
    const int swz = q ^ (r16 & 3) ^ ((r16 >> 2) & 3);   // global 16B-chunk
    const int srow = (wave << 5) + r16;                  // rows [32w,32w+16)
    const char* gA = (const char*)(A + (m_blk + srow) * (long)lda) + (swz << 4);
    const char* gW = (const char*)(W + (n_blk + srow) * (long)ldw) + (swz << 4);
    const long aRow16 = (long)lda * 32;   // +16 rows in bytes
    const long wRow16 = (long)ldw * 32;
    bf16* lA = As + (wave << 10);
    bf16* lW = Ws + (wave << 10);

    floatx4 zero = {0.f, 0.f, 0.f, 0.f};
    floatx4 acc[4][4];
#pragma unroll
    for (int i = 0; i < 4; i++)
#pragma unroll
        for (int j = 0; j < 4; j++) acc[i][j] = zero;

    const int mrow = (wave & 1) << 6;
    const int ncol = (wave >> 1) << 6;
    const short* AsS = (const short*)As;
    const short* WsS = (const short*)Ws;
    const int fm = lane & 15;
    const int fq = lane >> 4;                              // 0..3
    const int fke = (fq ^ (fm & 3) ^ ((fm >> 2) & 3)) << 3; // swizzled elem off

    for (int k0 = 0; k0 < K; k0 += 32) {
        __builtin_amdgcn_global_load_lds(
            (const __attribute__((address_space(1))) unsigned int*)gA,
            (__attribute__((address_space(3))) unsigned int*)lA, 16, 0, 0);
        __builtin_amdgcn_global_load_lds(
            (const __attribute__((address_space(1))) unsigned int*)(gA + aRow16),
            (__attribute__((address_space(3))) unsigned int*)(lA + 512), 16, 0, 0);
        __builtin_amdgcn_global_load_lds(
            (const __attribute__((address_space(1))) unsigned int*)gW,
            (__attribute__((address_space(3))) unsigned int*)(lW), 16, 0, 0);
        __builtin_amdgcn_global_load_lds(
            (const __attribute__((address_space(1))) unsigned int*)(gW + wRow16),
            (__attribute__((address_space(3))) unsigned int*)(lW + 512), 16, 0, 0);
        gA += 64; gW += 64;
        __syncthreads();

        short8 af[4], bfr[4];
#pragma unroll
        for (int i = 0; i < 4; i++) {
            af[i]  = *(const short8*)(AsS + (mrow + i * 16 + fm) * 32 + fke);
            bfr[i] = *(const short8*)(WsS + (ncol + i * 16 + fm) * 32 + fke);
        }
#pragma unroll
        for (int i = 0; i < 4; i++)
#pragma unroll
            for (int j = 0; j < 4; j++)
                acc[i][j] = __builtin_amdgcn_mfma_f32_16x16x32_bf16(
                    af[i], bfr[j], acc[i][j], 0, 0, 0);
        __syncthreads();
    }

    // epilogue: C/D layout col = lane&15, row = (lane>>4)*4 + reg
    const int crow0 = (lane >> 4) << 2;
    const int ccol = lane & 15;
#pragma unroll
    for (int i = 0; i < 4; i++) {
#pragma unroll
        for (int j = 0; j < 4; j++) {
            const long col = n_blk + ncol + j * 16 + ccol;
            const float bv = bias ? bias[col] : 0.f;
#pragma unroll
            for (int r = 0; r < 4; r++) {
                const long row = m_blk + mrow + i * 16 + crow0 + r;
                float v = acc[i][j][r] + bv;
                if (addv) v += addv[row * add_stride + col];
                if (c_fp32) ((float*)Cout)[row * (long)ldc + col] = v;
                else ((bf16*)Cout)[row * (long)ldc + col] = __float2bfloat16(v);
            }
        }
    }
}

// ---------------- pointwise ----------------
__device__ inline float sigf(float x) { return 1.f / (1.f + __expf(-x)); }
__device__ inline float tanh_fast(float x) { return 2.f / (1.f + __expf(-2.f * x)) - 1.f; }

__device__ inline void block_reduce4(float& a, float& b, float& c, float& d,
                                     float* s) {
#pragma unroll
    for (int off = 32; off > 0; off >>= 1) {
        a += __shfl_down(a, off, 64);
        b += __shfl_down(b, off, 64);
        c += __shfl_down(c, off, 64);
        d += __shfl_down(d, off, 64);
    }
    const int lane = threadIdx.x & 63, w = threadIdx.x >> 6;
    __syncthreads();
    if (lane == 0) { s[w] = a; s[w + 4] = b; s[w + 8] = c; s[w + 12] = d; }
    __syncthreads();
    a = s[0] + s[1] + s[2] + s[3];
    b = s[4] + s[5] + s[6] + s[7];
    c = s[8] + s[9] + s[10] + s[11];
    d = s[12] + s[13] + s[14] + s[15];
}

// Block handles sibling rows 2p,2p+1 (chunk-local). Writes h rows, and the
// next level's A_cat row [xs | h0+h1] at parent index.
__global__ __launch_bounds__(256) void pointwise_pair(
    const bf16* __restrict__ C, int ldc,       // chunk-local rows
    const bf16* __restrict__ fhb,              // chunk-local child rows / null
    const bf16* __restrict__ hprev2,           // hprev + 2*m0*H / null
    const float* __restrict__ x,
    const float* __restrict__ bfh,
    const float* __restrict__ gc, const float* __restrict__ bc,
    const float* __restrict__ gh, const float* __restrict__ bh,
    bf16* __restrict__ hout,                   // + m0*H
    bf16* __restrict__ Anext,                  // next level A_cat (global rows)
    int m0, int lp)                            // chunk offset, parent level
{
    __shared__ float sred[16];
    const int pl = blockIdx.x;
    const bf16* cr0 = C + (long)(2 * pl) * ldc;
    const bf16* cr1 = cr0 + ldc;
    float c0v[3], c1v[3], o0v[3], o1v[3], h0v[3], h1v[3];
    float s0 = 0.f, q0 = 0.f, s1 = 0.f, q1 = 0.f;
#pragma unroll
    for (int tI = 0; tI < 3; tI++) {
        const int j = threadIdx.x + tI * 256;
        const float i0 = sigf(b2f(cr0[j]));
        const float i1 = sigf(b2f(cr1[j]));
        o0v[tI] = b2f(cr0[Hdim + j]);
        o1v[tI] = b2f(cr1[Hdim + j]);
        float c0 = i0 * tanh_fast(b2f(cr0[2 * Hdim + j]));
        float c1 = i1 * tanh_fast(b2f(cr1[2 * Hdim + j]));
        if (fhb) {
            const float bfhj = bfh[j];
            const float fx0 = b2f(cr0[3 * Hdim + j]);
            const float fx1 = b2f(cr1[3 * Hdim + j]);
            const long base = (long)(4 * pl) * Hdim + j;
            const float f00 = sigf(fx0 + b2f(fhb[base]) + bfhj);
            const float f01 = sigf(fx0 + b2f(fhb[base + Hdim]) + bfhj);
            const float f10 = sigf(fx1 + b2f(fhb[base + 2 * Hdim]) + bfhj);
            const float f11 = sigf(fx1 + b2f(fhb[base + 3 * Hdim]) + bfhj);
            c0 += f00 * b2f(hprev2[base]) + f01 * b2f(hprev2[base + Hdim]);
            c1 += f10 * b2f(hprev2[base + 2 * Hdim]) + f11 * b2f(hprev2[base + 3 * Hdim]);
        }
        c0v[tI] = c0; c1v[tI] = c1;
        s0 += c0; q0 += c0 * c0; s1 += c1; q1 += c1 * c1;
    }
    block_reduce4(s0, q0, s1, q1, sred);
    const float m0c = s0 / Hdim, m1c = s1 / Hdim;
    const float r0c = rsqrtf(q0 / Hdim - m0c * m0c + 1e-5f);
    const float r1c = rsqrtf(q1 / Hdim - m1c * m1c + 1e-5f);
    float hs0 = 0.f, hq0 = 0.f, hs1 = 0.f, hq1 = 0.f;
#pragma unroll
    for (int tI = 0; tI < 3; tI++) {
        const int j = threadIdx.x + tI * 256;
        const float cn0 = (c0v[tI] - m0c) * r0c * gc[j] + bc[j];
        const float cn1 = (c1v[tI] - m1c) * r1c * gc[j] + bc[j];
        const float h0 = sigf(o0v[tI]) * tanh_fast(cn0);
        const float h1 = sigf(o1v[tI]) * tanh_fast(cn1);
        h0v[tI] = h0; h1v[tI] = h1;
        hs0 += h0; hq0 += h0 * h0; hs1 += h1; hq1 += h1 * h1;
    }
    block_reduce4(hs0, hq0, hs1, hq1, sred);
    const float mh0 = hs0 / Hdim, mh1 = hs1 / Hdim;
    const float rh0 = rsqrtf(hq0 / Hdim - mh0 * mh0 + 1e-5f);
    const float rh1 = rsqrtf(hq1 / Hdim - mh1 * mh1 + 1e-5f);

    const int pg = m0 / 2 + pl;                   // parent global index
    const int b = pg >> lp;
    const int jn = pg & ((1 << lp) - 1);
    const float* xr = x + ((long)b * 255 + (1 << lp) - 1 + jn) * Hdim;
    bf16* arow = Anext + (long)pg * 1536;
#pragma unroll
    for (int tI = 0; tI < 3; tI++) {
        const int j = threadIdx.x + tI * 256;
        const float h0 = (h0v[tI] - mh0) * rh0 * gh[j] + bh[j];
        const float h1 = (h1v[tI] - mh1) * rh1 * gh[j] + bh[j];
        hout[(long)(2 * pl) * Hdim + j] = __float2bfloat16(h0);
        hout[(long)(2 * pl + 1) * Hdim + j] = __float2bfloat16(h1);
        arow[768 + j] = __float2bfloat16(h0 + h1);
        arow[j] = __float2bfloat16(xr[j]);
    }
}

// root level: single row per block, no A write
__global__ __launch_bounds__(256) void pointwise_root(
    const bf16* __restrict__ C, int ldc,
    const bf16* __restrict__ fhb, const bf16* __restrict__ hprev,
    const float* __restrict__ bfh,
    const float* __restrict__ gc, const float* __restrict__ bc,
    const float* __restrict__ gh, const float* __restrict__ bh,
    bf16* __restrict__ hout)
{
    __shared__ float sred[16];
    const int m = blockIdx.x;
    const bf16* cr = C + (long)m * ldc;
    float cv[3], ov[3], hv[3];
    float ssum = 0.f, ssq = 0.f, d0 = 0.f, d1 = 0.f;
#pragma unroll
    for (int tI = 0; tI < 3; tI++) {
        const int j = threadIdx.x + tI * 256;
        const float i_ = sigf(b2f(cr[j]));
        ov[tI] = b2f(cr[Hdim + j]);
        float c = i_ * tanh_fast(b2f(cr[2 * Hdim + j]));
        const float fx = b2f(cr[3 * Hdim + j]);
        const float bfhj = bfh[j];
        const long base = (long)(2 * m) * Hdim + j;
        const float f0 = sigf(fx + b2f(fhb[base]) + bfhj);
        const float f1 = sigf(fx + b2f(fhb[base + Hdim]) + bfhj);
        c += f0 * b2f(hprev[base]) + f1 * b2f(hprev[base + Hdim]);
        cv[tI] = c; ssum += c; ssq += c * c;
    }
    block_reduce4(ssum, ssq, d0, d1, sred);
    const float mean = ssum / Hdim;
    const float rstd = rsqrtf(ssq / Hdim - mean * mean + 1e-5f);
    float hs = 0.f, hq = 0.f;
#pragma unroll
    for (int tI = 0; tI < 3; tI++) {
        const int j = threadIdx.x + tI * 256;
        const float cn = (cv[tI] - mean) * rstd * gc[j] + bc[j];
        const float h = sigf(ov[tI]) * tanh_fast(cn);
        hv[tI] = h; hs += h; hq += h * h;
    }
    d0 = 0.f; d1 = 0.f;
    block_reduce4(hs, hq, d0, d1, sred);
    const float mh = hs / Hdim;
    const float rh = rsqrtf(hq / Hdim - mh * mh + 1e-5f);
#pragma unroll
    for (int tI = 0; tI < 3; tI++) {
        const int j = threadIdx.x + tI * 256;
        hout[(long)m * Hdim + j] = __float2bfloat16((hv[tI] - mh) * rh * gh[j] + bh[j]);
    }
}

// ---------------- launch ----------------
extern "C" void kernel_launch(void* const* d_in, const int* in_sizes, int n_in,
                              void* d_out, int out_size, void* d_ws, size_t ws_size,
                              hipStream_t stream) {
    (void)in_sizes; (void)n_in; (void)out_size; (void)ws_size;
    const float* x      = (const float*)d_in[0];
    const float* Wioux  = (const float*)d_in[1];
    const float* b_ioux = (const float*)d_in[2];
    const float* Wiouh  = (const float*)d_in[3];
    const float* Wfx    = (const float*)d_in[4];
    const float* b_fx   = (const float*)d_in[5];
    const float* Wfh    = (const float*)d_in[6];
    const float* b_fh   = (const float*)d_in[7];
    const float* ln_c_g = (const float*)d_in[8];
    const float* ln_c_b = (const float*)d_in[9];
    const float* ln_h_g = (const float*)d_in[10];
    const float* ln_h_b = (const float*)d_in[11];
    const float* Wout   = (const float*)d_in[12];
    const float* b_out  = (const float*)d_in[13];
    float* out = (float*)d_out;

    // ---- workspace (~212 MB) ----
    char* p = (char*)d_ws;
    bf16* W_cat   = (bf16*)p; p += 8L * 3072 * 1536 * 2;   // 75.5 MB
    bf16* Wfh_bf  = (bf16*)p; p += 8L * 768 * 768 * 2;     //  9.4 MB
    bf16* Wout_bf = (bf16*)p; p += 768L * 768 * 2;         //  1.2 MB
    float* b_cat  = (float*)p; p += 8L * 3072 * 4;         //  0.1 MB
    bf16* leafA   = (bf16*)p; p += 16384L * 768 * 2;       // 25.2 MB (fhb overlay)
    bf16* A6      = (bf16*)p; p += 8192L * 1536 * 2;       // 25.2 MB
    bf16* A5      = (bf16*)p; p += 4096L * 1536 * 2;       // 12.6 MB
    bf16* Cbuf    = (bf16*)p; p += 4096L * 3072 * 2;       // 25.2 MB
    bf16* hA      = (bf16*)p; p += 16384L * 768 * 2;       // 25.2 MB
    bf16* hB      = (bf16*)p; p += 8192L * 768 * 2;        // 12.6 MB
    bf16* fhb     = leafA;  // leafA dead once leaf GEMMs complete

    // ---- weight prep ----
    conv_wcat<<<8 * 3072, 384, 0, stream>>>(Wioux, Wiouh, Wfx, W_cat);
    conv_f2b<<<4608, 256, 0, stream>>>(Wfh, Wfh_bf, 8L * 768 * 768 / 4);
    conv_f2b<<<576, 256, 0, stream>>>(Wout, Wout_bf, 768L * 768 / 4);
    build_bcat<<<96, 256, 0, stream>>>(b_ioux, b_fx, b_cat);
    conv_leaf<<<16384, 192, 0, stream>>>(x, leafA);

    const int CH = 4096;

    // ---- leaf level l=7 (M=16384, 4 chunks) ----
    for (int c = 0; c < 4; c++) {
        const int m0 = c * CH;
        gemm_mfma<<<dim3(18, CH / 128), 256, 0, stream>>>(
            leafA + (long)m0 * 768, 768, W_cat + 7L * 3072 * 1536, 1536,
            b_cat + 7 * 3072, Cbuf, 2304, 0, 768, nullptr, 0);
        pointwise_pair<<<CH / 2, 256, 0, stream>>>(
            Cbuf, 2304, nullptr, nullptr, x, nullptr,
            ln_c_g + 7 * Hdim, ln_c_b + 7 * Hdim, ln_h_g + 7 * Hdim, ln_h_b + 7 * Hdim,
            hA + (long)m0 * Hdim, A6, m0, 6);
    }

    // ---- levels 6..1 ----
    bf16* hp = hA; bf16* hc = hB;
    bf16* Acur = A6; bf16* Anxt = A5;
    for (int l = 6; l >= 1; l--) {
        const int M = 128 << l;
        const int Mc = (M < CH) ? M : CH;
        const int nch = M / Mc;
        for (int c = 0; c < nch; c++) {
            const int m0 = c * Mc;
            gemm_mfma<<<dim3(24, Mc / 128), 256, 0, stream>>>(
                Acur + (long)m0 * 1536, 1536, W_cat + (long)l * 3072 * 1536, 1536,
                b_cat + l * 3072, Cbuf, 3072, 0, 1536, nullptr, 0);
            gemm_mfma<<<dim3(6, 2 * Mc / 128), 256, 0, stream>>>(
                hp + (long)2 * m0 * Hdim, 768, Wfh_bf + (long)l * 768 * 768, 768,
                nullptr, fhb, 768, 0, 768, nullptr, 0);
            pointwise_pair<<<Mc / 2, 256, 0, stream>>>(
                Cbuf, 3072, fhb, hp + (long)2 * m0 * Hdim, x, b_fh + l * Hdim,
                ln_c_g + l * Hdim, ln_c_b + l * Hdim, ln_h_g + l * Hdim, ln_h_b + l * Hdim,
                hc + (long)m0 * Hdim, Anxt, m0, l - 1);
        }
        bf16* t1 = hp; hp = hc; hc = t1;
        bf16* t2 = Acur; Acur = Anxt; Anxt = t2;
    }

    // ---- root level l=0 (M=128) ----
    gemm_mfma<<<dim3(24, 1), 256, 0, stream>>>(
        Acur, 1536, W_cat, 1536, b_cat, Cbuf, 3072, 0, 1536, nullptr, 0);
    gemm_mfma<<<dim3(6, 2), 256, 0, stream>>>(
        hp, 768, Wfh_bf, 768, nullptr, fhb, 768, 0, 768, nullptr, 0);
    pointwise_root<<<128, 256, 0, stream>>>(
        Cbuf, 3072, fhb, hp, b_fh,
        ln_c_g, ln_c_b, ln_h_g, ln_h_b, hc);

    // ---- out = h_root @ Wout^T + b_out + x[:,0] ----
    gemm_mfma<<<dim3(6, 1), 256, 0, stream>>>(
        hc, 768, Wout_bf, 768, b_out, out, 768, 1, 768, x, 255L * 768);
}

// Round 4
// 1056.461 us; speedup vs baseline: 3.9506x; 1.1414x over previous
//
#include <hip/hip_runtime.h>
#include <hip/hip_bf16.h>

// TreeLSTM (child-sum, complete binary tree, DEPTH=8) on MI355X.
// Round 4: dual-descriptor GEMM launches (iou+fh in one grid), swizzle
// reverted (R3 showed SQ_LDS_BANK_CONFLICT is a structural 4/ds_read_b128,
// not actionable; swizzle cost +3us/dispatch), prep kernels merged.

#define Hdim 768

typedef __hip_bfloat16 bf16;
typedef __attribute__((ext_vector_type(8))) short short8;
typedef __attribute__((ext_vector_type(4))) float floatx4;

__device__ inline float b2f(unsigned short u) {
    union { unsigned int i; float f; } v; v.i = ((unsigned int)u) << 16; return v.f;
}
__device__ inline float b2f(bf16 h) { return b2f(*(unsigned short*)&h); }
__device__ inline unsigned short f2bu(float f) {
    bf16 h = __float2bfloat16(f);
    return *(unsigned short*)&h;
}
__device__ inline ushort4 cvt4(float4 v) {
    ushort4 o; o.x = f2bu(v.x); o.y = f2bu(v.y); o.z = f2bu(v.z); o.w = f2bu(v.w);
    return o;
}

// ---------------- weight prep ----------------
// W_cat[l] : [3072][1536] = [[Wioux[l] | Wiouh[l]]; [Wfx[l] | 0]]
__global__ __launch_bounds__(384) void conv_wcat(
    const float* __restrict__ Wioux, const float* __restrict__ Wiouh,
    const float* __restrict__ Wfx, bf16* __restrict__ W_cat)
{
    const int row = blockIdx.x;          // 0 .. 8*3072-1
    const int l = row / 3072;
    const int g = row % 3072;
    const int t = threadIdx.x;
    const int k2 = t << 2;
    float4 v;
    if (g < 2304) {
        const float* src = (k2 < 768)
            ? Wioux + ((long)l * 2304 + g) * 768 + k2
            : Wiouh + ((long)l * 2304 + g) * 768 + (k2 - 768);
        v = *(const float4*)src;
    } else if (k2 < 768) {
        v = *(const float4*)(Wfx + ((long)l * 768 + (g - 2304)) * 768 + k2);
    } else {
        v = make_float4(0.f, 0.f, 0.f, 0.f);
    }
    ((ushort4*)(W_cat + (long)row * 1536))[t] = cvt4(v);
}

// Merged prep: Wfh f2b [0,4608) | Wout f2b [4608,5184) | b_cat [5184,5280)
//            | leaf conv [5280, 5280+16384)
__global__ __launch_bounds__(256) void prep_misc(
    const float* __restrict__ Wfh, const float* __restrict__ Wout,
    const float* __restrict__ b_ioux, const float* __restrict__ b_fx,
    const float* __restrict__ x,
    bf16* __restrict__ Wfh_bf, bf16* __restrict__ Wout_bf,
    float* __restrict__ b_cat, bf16* __restrict__ leafA)
{
    const int id = blockIdx.x;
    const int t = threadIdx.x;
    if (id < 4608) {
        const long i = (long)id * 256 + t;
        ((ushort4*)Wfh_bf)[i] = cvt4(((const float4*)Wfh)[i]);
    } else if (id < 5184) {
        const long i = (long)(id - 4608) * 256 + t;
        ((ushort4*)Wout_bf)[i] = cvt4(((const float4*)Wout)[i]);
    } else if (id < 5280) {
        const int i = (id - 5184) * 256 + t;   // 0..24575
        const int l = i / 3072, g = i % 3072;
        b_cat[i] = (g < 2304) ? b_ioux[l * 2304 + g] : b_fx[l * 768 + (g - 2304)];
    } else if (t < 192) {
        const int m = id - 5280;               // 0..16383
        const int b = m >> 7, j = m & 127;
        const float* xr = x + ((long)b * 255 + 127 + j) * Hdim;
        ((ushort4*)(leafA + (long)m * Hdim))[t] = cvt4(((const float4*)xr)[t]);
    }
}

// ---------------- MFMA GEMM (dual descriptor) ----------------
struct GemmDesc {
    const bf16* A; int lda;
    const bf16* W; int ldw;
    const float* bias;
    void* C; int ldc; int c_fp32;
    int K; int nxb;                      // n-blocks (N/128 .. or N/128*? = N/128*? )
    const float* addv; long add_stride;
};

// 128x128 tile, BK=32, 256 thr = 4 waves, 4x4 16x16x32 MFMA per wave.
__global__ __launch_bounds__(256) void gemm_dual(GemmDesc da, int na, GemmDesc db)
{
    __shared__ __align__(16) bf16 As[128 * 32];
    __shared__ __align__(16) bf16 Ws[128 * 32];
    int id = blockIdx.x;
    const bool second = (id >= na);
    if (second) id -= na;
    const GemmDesc d = second ? db : da;
    const int bm = id / d.nxb, bn = id % d.nxb;

    const int t = threadIdx.x;
    const int wave = t >> 6, lane = t & 63;
    const long m_blk = (long)bm << 7;
    const long n_blk = (long)bn << 7;

    // staging: wave w covers tile rows [32w, 32w+32), two 16-row instrs
    const int srow = (wave << 5) + (lane >> 2);
    const int sbyte = (lane & 3) << 4;
    const char* gA = (const char*)(d.A + (m_blk + srow) * (long)d.lda) + sbyte;
    const char* gW = (const char*)(d.W + (n_blk + srow) * (long)d.ldw) + sbyte;
    const long aRow16 = (long)d.lda * 32;
    const long wRow16 = (long)d.ldw * 32;
    bf16* lA = As + (wave << 10);
    bf16* lW = Ws + (wave << 10);

    floatx4 zero = {0.f, 0.f, 0.f, 0.f};
    floatx4 acc[4][4];
#pragma unroll
    for (int i = 0; i < 4; i++)
#pragma unroll
        for (int j = 0; j < 4; j++) acc[i][j] = zero;

    const int mrow = (wave & 1) << 6;
    const int ncol = (wave >> 1) << 6;
    const short* AsS = (const short*)As;
    const short* WsS = (const short*)Ws;
    const int fm = lane & 15;
    const int fk = (lane >> 4) << 3;

    for (int k0 = 0; k0 < d.K; k0 += 32) {
        __builtin_amdgcn_global_load_lds(
            (const __attribute__((address_space(1))) unsigned int*)gA,
            (__attribute__((address_space(3))) unsigned int*)lA, 16, 0, 0);
        __builtin_amdgcn_global_load_lds(
            (const __attribute__((address_space(1))) unsigned int*)(gA + aRow16),
            (__attribute__((address_space(3))) unsigned int*)(lA + 512), 16, 0, 0);
        __builtin_amdgcn_global_load_lds(
            (const __attribute__((address_space(1))) unsigned int*)gW,
            (__attribute__((address_space(3))) unsigned int*)lW, 16, 0, 0);
        __builtin_amdgcn_global_load_lds(
            (const __attribute__((address_space(1))) unsigned int*)(gW + wRow16),
            (__attribute__((address_space(3))) unsigned int*)(lW + 512), 16, 0, 0);
        gA += 64; gW += 64;
        __syncthreads();

        short8 af[4], bfr[4];
#pragma unroll
        for (int i = 0; i < 4; i++) {
            af[i]  = *(const short8*)(AsS + (mrow + i * 16 + fm) * 32 + fk);
            bfr[i] = *(const short8*)(WsS + (ncol + i * 16 + fm) * 32 + fk);
        }
#pragma unroll
        for (int i = 0; i < 4; i++)
#pragma unroll
            for (int j = 0; j < 4; j++)
                acc[i][j] = __builtin_amdgcn_mfma_f32_16x16x32_bf16(
                    af[i], bfr[j], acc[i][j], 0, 0, 0);
        __syncthreads();
    }

    // epilogue: C/D layout col = lane&15, row = (lane>>4)*4 + reg
    const int crow0 = (lane >> 4) << 2;
    const int ccol = lane & 15;
#pragma unroll
    for (int i = 0; i < 4; i++) {
#pragma unroll
        for (int j = 0; j < 4; j++) {
            const long col = n_blk + ncol + j * 16 + ccol;
            const float bv = d.bias ? d.bias[col] : 0.f;
#pragma unroll
            for (int r = 0; r < 4; r++) {
                const long row = m_blk + mrow + i * 16 + crow0 + r;
                float v = acc[i][j][r] + bv;
                if (d.addv) v += d.addv[row * d.add_stride + col];
                if (d.c_fp32) ((float*)d.C)[row * (long)d.ldc + col] = v;
                else ((bf16*)d.C)[row * (long)d.ldc + col] = __float2bfloat16(v);
            }
        }
    }
}

static inline GemmDesc mkdesc(const bf16* A, int lda, const bf16* W, int ldw,
                              const float* bias, void* C, int ldc, int c_fp32,
                              int K, int nxb, const float* addv, long add_stride) {
    GemmDesc d; d.A = A; d.lda = lda; d.W = W; d.ldw = ldw; d.bias = bias;
    d.C = C; d.ldc = ldc; d.c_fp32 = c_fp32; d.K = K; d.nxb = nxb;
    d.addv = addv; d.add_stride = add_stride; return d;
}

// ---------------- pointwise ----------------
__device__ inline float sigf(float x) { return 1.f / (1.f + __expf(-x)); }
__device__ inline float tanh_fast(float x) { return 2.f / (1.f + __expf(-2.f * x)) - 1.f; }

__device__ inline void block_reduce4(float& a, float& b, float& c, float& d,
                                     float* s) {
#pragma unroll
    for (int off = 32; off > 0; off >>= 1) {
        a += __shfl_down(a, off, 64);
        b += __shfl_down(b, off, 64);
        c += __shfl_down(c, off, 64);
        d += __shfl_down(d, off, 64);
    }
    const int lane = threadIdx.x & 63, w = threadIdx.x >> 6;
    __syncthreads();
    if (lane == 0) { s[w] = a; s[w + 4] = b; s[w + 8] = c; s[w + 12] = d; }
    __syncthreads();
    a = s[0] + s[1] + s[2] + s[3];
    b = s[4] + s[5] + s[6] + s[7];
    c = s[8] + s[9] + s[10] + s[11];
    d = s[12] + s[13] + s[14] + s[15];
}

// Block handles sibling rows 2p,2p+1 (chunk-local). Writes h rows and the
// next level's A_cat row [xs | h0+h1] at parent index.
__global__ __launch_bounds__(256) void pointwise_pair(
    const bf16* __restrict__ C, int ldc,
    const bf16* __restrict__ fhb,
    const bf16* __restrict__ hprev2,
    const float* __restrict__ x,
    const float* __restrict__ bfh,
    const float* __restrict__ gc, const float* __restrict__ bc,
    const float* __restrict__ gh, const float* __restrict__ bh,
    bf16* __restrict__ hout,
    bf16* __restrict__ Anext,
    int m0, int lp)
{
    __shared__ float sred[16];
    const int pl = blockIdx.x;
    const bf16* cr0 = C + (long)(2 * pl) * ldc;
    const bf16* cr1 = cr0 + ldc;
    float c0v[3], c1v[3], o0v[3], o1v[3], h0v[3], h1v[3];
    float s0 = 0.f, q0 = 0.f, s1 = 0.f, q1 = 0.f;
#pragma unroll
    for (int tI = 0; tI < 3; tI++) {
        const int j = threadIdx.x + tI * 256;
        const float i0 = sigf(b2f(cr0[j]));
        const float i1 = sigf(b2f(cr1[j]));
        o0v[tI] = b2f(cr0[Hdim + j]);
        o1v[tI] = b2f(cr1[Hdim + j]);
        float c0 = i0 * tanh_fast(b2f(cr0[2 * Hdim + j]));
        float c1 = i1 * tanh_fast(b2f(cr1[2 * Hdim + j]));
        if (fhb) {
            const float bfhj = bfh[j];
            const float fx0 = b2f(cr0[3 * Hdim + j]);
            const float fx1 = b2f(cr1[3 * Hdim + j]);
            const long base = (long)(4 * pl) * Hdim + j;
            const float f00 = sigf(fx0 + b2f(fhb[base]) + bfhj);
            const float f01 = sigf(fx0 + b2f(fhb[base + Hdim]) + bfhj);
            const float f10 = sigf(fx1 + b2f(fhb[base + 2 * Hdim]) + bfhj);
            const float f11 = sigf(fx1 + b2f(fhb[base + 3 * Hdim]) + bfhj);
            c0 += f00 * b2f(hprev2[base]) + f01 * b2f(hprev2[base + Hdim]);
            c1 += f10 * b2f(hprev2[base + 2 * Hdim]) + f11 * b2f(hprev2[base + 3 * Hdim]);
        }
        c0v[tI] = c0; c1v[tI] = c1;
        s0 += c0; q0 += c0 * c0; s1 += c1; q1 += c1 * c1;
    }
    block_reduce4(s0, q0, s1, q1, sred);
    const float m0c = s0 / Hdim, m1c = s1 / Hdim;
    const float r0c = rsqrtf(q0 / Hdim - m0c * m0c + 1e-5f);
    const float r1c = rsqrtf(q1 / Hdim - m1c * m1c + 1e-5f);
    float hs0 = 0.f, hq0 = 0.f, hs1 = 0.f, hq1 = 0.f;
#pragma unroll
    for (int tI = 0; tI < 3; tI++) {
        const int j = threadIdx.x + tI * 256;
        const float cn0 = (c0v[tI] - m0c) * r0c * gc[j] + bc[j];
        const float cn1 = (c1v[tI] - m1c) * r1c * gc[j] + bc[j];
        const float h0 = sigf(o0v[tI]) * tanh_fast(cn0);
        const float h1 = sigf(o1v[tI]) * tanh_fast(cn1);
        h0v[tI] = h0; h1v[tI] = h1;
        hs0 += h0; hq0 += h0 * h0; hs1 += h1; hq1 += h1 * h1;
    }
    block_reduce4(hs0, hq0, hs1, hq1, sred);
    const float mh0 = hs0 / Hdim, mh1 = hs1 / Hdim;
    const float rh0 = rsqrtf(hq0 / Hdim - mh0 * mh0 + 1e-5f);
    const float rh1 = rsqrtf(hq1 / Hdim - mh1 * mh1 + 1e-5f);

    const int pg = m0 / 2 + pl;
    const int b = pg >> lp;
    const int jn = pg & ((1 << lp) - 1);
    const float* xr = x + ((long)b * 255 + (1 << lp) - 1 + jn) * Hdim;
    bf16* arow = Anext + (long)pg * 1536;
#pragma unroll
    for (int tI = 0; tI < 3; tI++) {
        const int j = threadIdx.x + tI * 256;
        const float h0 = (h0v[tI] - mh0) * rh0 * gh[j] + bh[j];
        const float h1 = (h1v[tI] - mh1) * rh1 * gh[j] + bh[j];
        hout[(long)(2 * pl) * Hdim + j] = __float2bfloat16(h0);
        hout[(long)(2 * pl + 1) * Hdim + j] = __float2bfloat16(h1);
        arow[768 + j] = __float2bfloat16(h0 + h1);
        arow[j] = __float2bfloat16(xr[j]);
    }
}

__global__ __launch_bounds__(256) void pointwise_root(
    const bf16* __restrict__ C, int ldc,
    const bf16* __restrict__ fhb, const bf16* __restrict__ hprev,
    const float* __restrict__ bfh,
    const float* __restrict__ gc, const float* __restrict__ bc,
    const float* __restrict__ gh, const float* __restrict__ bh,
    bf16* __restrict__ hout)
{
    __shared__ float sred[16];
    const int m = blockIdx.x;
    const bf16* cr = C + (long)m * ldc;
    float cv[3], ov[3], hv[3];
    float ssum = 0.f, ssq = 0.f, d0 = 0.f, d1 = 0.f;
#pragma unroll
    for (int tI = 0; tI < 3; tI++) {
        const int j = threadIdx.x + tI * 256;
        const float i_ = sigf(b2f(cr[j]));
        ov[tI] = b2f(cr[Hdim + j]);
        float c = i_ * tanh_fast(b2f(cr[2 * Hdim + j]));
        const float fx = b2f(cr[3 * Hdim + j]);
        const float bfhj = bfh[j];
        const long base = (long)(2 * m) * Hdim + j;
        const float f0 = sigf(fx + b2f(fhb[base]) + bfhj);
        const float f1 = sigf(fx + b2f(fhb[base + Hdim]) + bfhj);
        c += f0 * b2f(hprev[base]) + f1 * b2f(hprev[base + Hdim]);
        cv[tI] = c; ssum += c; ssq += c * c;
    }
    block_reduce4(ssum, ssq, d0, d1, sred);
    const float mean = ssum / Hdim;
    const float rstd = rsqrtf(ssq / Hdim - mean * mean + 1e-5f);
    float hs = 0.f, hq = 0.f;
#pragma unroll
    for (int tI = 0; tI < 3; tI++) {
        const int j = threadIdx.x + tI * 256;
        const float cn = (cv[tI] - mean) * rstd * gc[j] + bc[j];
        const float h = sigf(ov[tI]) * tanh_fast(cn);
        hv[tI] = h; hs += h; hq += h * h;
    }
    d0 = 0.f; d1 = 0.f;
    block_reduce4(hs, hq, d0, d1, sred);
    const float mh = hs / Hdim;
    const float rh = rsqrtf(hq / Hdim - mh * mh + 1e-5f);
#pragma unroll
    for (int tI = 0; tI < 3; tI++) {
        const int j = threadIdx.x + tI * 256;
        hout[(long)m * Hdim + j] = __float2bfloat16((hv[tI] - mh) * rh * gh[j] + bh[j]);
    }
}

// ---------------- launch ----------------
extern "C" void kernel_launch(void* const* d_in, const int* in_sizes, int n_in,
                              void* d_out, int out_size, void* d_ws, size_t ws_size,
                              hipStream_t stream) {
    (void)in_sizes; (void)n_in; (void)out_size; (void)ws_size;
    const float* x      = (const float*)d_in[0];
    const float* Wioux  = (const float*)d_in[1];
    const float* b_ioux = (const float*)d_in[2];
    const float* Wiouh  = (const float*)d_in[3];
    const float* Wfx    = (const float*)d_in[4];
    const float* b_fx   = (const float*)d_in[5];
    const float* Wfh    = (const float*)d_in[6];
    const float* b_fh   = (const float*)d_in[7];
    const float* ln_c_g = (const float*)d_in[8];
    const float* ln_c_b = (const float*)d_in[9];
    const float* ln_h_g = (const float*)d_in[10];
    const float* ln_h_b = (const float*)d_in[11];
    const float* Wout   = (const float*)d_in[12];
    const float* b_out  = (const float*)d_in[13];
    float* out = (float*)d_out;

    // ---- workspace (~212 MB) ----
    char* p = (char*)d_ws;
    bf16* W_cat   = (bf16*)p; p += 8L * 3072 * 1536 * 2;   // 75.5 MB
    bf16* Wfh_bf  = (bf16*)p; p += 8L * 768 * 768 * 2;     //  9.4 MB
    bf16* Wout_bf = (bf16*)p; p += 768L * 768 * 2;         //  1.2 MB
    float* b_cat  = (float*)p; p += 8L * 3072 * 4;         //  0.1 MB
    bf16* leafA   = (bf16*)p; p += 16384L * 768 * 2;       // 25.2 MB (fhb overlay)
    bf16* A6      = (bf16*)p; p += 8192L * 1536 * 2;       // 25.2 MB
    bf16* A5      = (bf16*)p; p += 4096L * 1536 * 2;       // 12.6 MB
    bf16* Cbuf    = (bf16*)p; p += 4096L * 3072 * 2;       // 25.2 MB
    bf16* hA      = (bf16*)p; p += 16384L * 768 * 2;       // 25.2 MB
    bf16* hB      = (bf16*)p; p += 8192L * 768 * 2;        // 12.6 MB
    bf16* fhb     = leafA;  // leafA dead once leaf GEMMs complete

    // ---- prep (2 launches) ----
    conv_wcat<<<8 * 3072, 384, 0, stream>>>(Wioux, Wiouh, Wfx, W_cat);
    prep_misc<<<5280 + 16384, 256, 0, stream>>>(
        Wfh, Wout, b_ioux, b_fx, x, Wfh_bf, Wout_bf, b_cat, leafA);

    const int CH = 4096;
    GemmDesc dummy = mkdesc(nullptr, 0, nullptr, 0, nullptr, nullptr, 0, 0, 0, 1,
                            nullptr, 0);

    // ---- leaf level l=7 (M=16384, 4 chunks) ----
    for (int c = 0; c < 4; c++) {
        const int m0 = c * CH;
        GemmDesc d = mkdesc(leafA + (long)m0 * 768, 768,
                            W_cat + 7L * 3072 * 1536, 1536, b_cat + 7 * 3072,
                            Cbuf, 2304, 0, 768, 18, nullptr, 0);
        gemm_dual<<<18 * (CH / 128), 256, 0, stream>>>(d, 18 * (CH / 128), dummy);
        pointwise_pair<<<CH / 2, 256, 0, stream>>>(
            Cbuf, 2304, nullptr, nullptr, x, nullptr,
            ln_c_g + 7 * Hdim, ln_c_b + 7 * Hdim, ln_h_g + 7 * Hdim, ln_h_b + 7 * Hdim,
            hA + (long)m0 * Hdim, A6, m0, 6);
    }

    // ---- levels 6..1: dual GEMM (iou + fh) then pointwise ----
    bf16* hp = hA; bf16* hc = hB;
    bf16* Acur = A6; bf16* Anxt = A5;
    for (int l = 6; l >= 1; l--) {
        const int M = 128 << l;
        const int Mc = (M < CH) ? M : CH;
        const int nch = M / Mc;
        for (int c = 0; c < nch; c++) {
            const int m0 = c * Mc;
            GemmDesc diou = mkdesc(Acur + (long)m0 * 1536, 1536,
                                   W_cat + (long)l * 3072 * 1536, 1536,
                                   b_cat + l * 3072, Cbuf, 3072, 0, 1536, 24,
                                   nullptr, 0);
            GemmDesc dfh = mkdesc(hp + (long)2 * m0 * Hdim, 768,
                                  Wfh_bf + (long)l * 768 * 768, 768, nullptr,
                                  fhb, 768, 0, 768, 6, nullptr, 0);
            const int na = 24 * (Mc / 128);
            const int nb = 6 * (2 * Mc / 128);
            gemm_dual<<<na + nb, 256, 0, stream>>>(diou, na, dfh);
            pointwise_pair<<<Mc / 2, 256, 0, stream>>>(
                Cbuf, 3072, fhb, hp + (long)2 * m0 * Hdim, x, b_fh + l * Hdim,
                ln_c_g + l * Hdim, ln_c_b + l * Hdim, ln_h_g + l * Hdim, ln_h_b + l * Hdim,
                hc + (long)m0 * Hdim, Anxt, m0, l - 1);
        }
        bf16* t1 = hp; hp = hc; hc = t1;
        bf16* t2 = Acur; Acur = Anxt; Anxt = t2;
    }

    // ---- root level l=0 (M=128) ----
    {
        GemmDesc diou = mkdesc(Acur, 1536, W_cat, 1536, b_cat, Cbuf, 3072, 0,
                               1536, 24, nullptr, 0);
        GemmDesc dfh = mkdesc(hp, 768, Wfh_bf, 768, nullptr, fhb, 768, 0,
                              768, 6, nullptr, 0);
        gemm_dual<<<24 + 12, 256, 0, stream>>>(diou, 24, dfh);
        pointwise_root<<<128, 256, 0, stream>>>(
            Cbuf, 3072, fhb, hp, b_fh,
            ln_c_g, ln_c_b, ln_h_g, ln_h_b, hc);
    }

    // ---- out = h_root @ Wout^T + b_out + x[:,0] ----
    {
        GemmDesc dout = mkdesc(hc, 768, Wout_bf, 768, b_out, out, 768, 1,
                               768, 6, x, 255L * 768);
        gemm_dual<<<6, 256, 0, stream>>>(dout, 6, dummy);
    }
}